// Round 2
// baseline (96272.174 us; speedup 1.0000x reference)
//
#include <hip/hip_runtime.h>
#include <math.h>

// Deep Reservoir Memory Network forward, MI355X persistent-dataflow kernel.
// Round 2: register-blocked dots (2x2 per thread, K split 4-way in-wave),
//          2-deep LLC prefetch, buffer-free flag waits sunk to the write.
//
// Structure: ONE persistent kernel, 256 blocks x 512 threads, 5 dataflow sets,
// weights resident in LDS (128 KiB/block), state exchanged via agent-scope
// (sc1/LLC) atomics with per-tick flag counters, double-buffered by parity.
//
// Round-2 changes vs round 1 (which hit 79 ms, VALUBusy 40%, 9.4e8 LDS
// conflicts):
//   * matdot: wave tile = 8 rows x 8 cols; each thread owns a 2x2 output
//     block and 1/4 of K (kp = lane>>4). 16 FMA per 4 ds_read_b128 (was 8
//     FMA per 4) -> half the LDS instructions, 64 KB (not 80 KB) LDS bytes
//     per wave per matdot. Final 4-way K reduction = 2x __shfl_xor.
//   * Weight LDS layout swizzled: slot = k4*16 + ((c + (k4&3)) & 15) so the
//     4 kp groups' column reads land on different bank quads (<=2-way).
//     State buffer row stride = 34 granules -> <=2-way on all reads/writes.
//   * 2-deep register prefetch of state chunks (two St register sets):
//     ~800 cy LLC latency now covered by 2 chunks of compute.
//   * Buffer-free waits (m2c[t-2] in M1, h1c/h2c[t-2] in M2, h2c[t-2] in H1)
//     moved from tick-top to just before the state write: upstream compute
//     now overlaps downstream tails -> the 5-stage chain pipelines.
//
// Sets (blockIdx.x):
//   [0,32)    M1 : m1_new = m1_old@Vm1^T + x_t@Wm1^T          (32 cols/blk)
//   [32,96)   M2 : m2_new = m2_old@Vm2^T + m1_new@Wm2^T       (16 cols/blk)
//   [96,160)  H1 : h1_new = .5*h1 + .5*tanh(x@Win1^T + h1@Wh1^T
//                                           + m2_new@Wmh1^T + b1)
//   [160,224) H2 : h2_new = .5*h2 + .5*tanh(g2a + h1_new@Win2^T
//                                           + m2_new@Wmh2^T)   (+ write out)
//   [224,256) G2 : g2a = h2_old@Wh2^T + b2                     (32 cols/blk)
//
// LDS (dynamic, 148480 B): float4 w4[8192] weights; float4 sbuf[32*34] state
// chunk (rows stride 34 granules).

#define BB 32
#define TT 2048
#define II 64
#define MM 1024
#define HHH 1024
#define ALEAK 0.5f
#define NTHREADS 512
#define SPIN_CAP 5000

#define SCOPE __HIP_MEMORY_SCOPE_AGENT

typedef unsigned long long u64;

__device__ __forceinline__ float lda(const float* p) {
  return __hip_atomic_load(p, __ATOMIC_RELAXED, SCOPE);
}
__device__ __forceinline__ u64 lda64(const u64* p) {
  return __hip_atomic_load(p, __ATOMIC_RELAXED, SCOPE);
}
__device__ __forceinline__ void sta(float* p, float v) {
  __hip_atomic_store(p, v, __ATOMIC_RELAXED, SCOPE);
}

// lane0 spins on a device-scope flag; capped so a sync bug can't hang the GPU.
__device__ __forceinline__ void wait_flag(int* f, int target) {
  if (threadIdx.x == 0) {
    int it = 0;
    while (__hip_atomic_load(f, __ATOMIC_RELAXED, SCOPE) < target) {
      __builtin_amdgcn_s_sleep(2);
      if (++it > SPIN_CAP) break;  // fail loud (wrong answer), not a timeout
    }
  }
  __syncthreads();
}

__device__ __forceinline__ void post_flag(int* f) {
  __syncthreads();  // drains each wave's vmcnt -> all sc1 stores at LLC
  if (threadIdx.x == 0) {
    __hip_atomic_fetch_add(f, 1, __ATOMIC_RELEASE, SCOPE);
  }
}

// lgkm-only barrier: orders LDS ops across the block WITHOUT draining vmcnt,
// so prefetched global (sc1) loads stay in flight across it.
__device__ __forceinline__ void barrier_lds() {
  asm volatile("s_waitcnt lgkmcnt(0)" ::: "memory");
  __builtin_amdgcn_s_barrier();
  asm volatile("" ::: "memory");
}

#define FMA4(A, S, W)      \
  A = fmaf(S.x, W.x, A);   \
  A = fmaf(S.y, W.y, A);   \
  A = fmaf(S.z, W.z, A);   \
  A = fmaf(S.w, W.w, A);

union Q2 { u64 q[2]; float4 f; };
struct St { Q2 r0, r1; };

// Per-thread geometry.
// lane: kp = lane>>4 (K quarter), rp2 = (lane>>2)&3, cp2 = lane&3.
// wave tile: 8 rows x 8 cols; block tile: 32 rows x 16 cols (8 waves, 4x2).
struct TMap {
  int sg0, sg1;  // sbuf read granule bases: r*34 + kp
  int w0, w1;    // weight granule offsets: kp*16 + ((c+kp)&15)
  int ws0, ws1;  // sbuf staging-write granules
  int rs0, gs;   // staging row (and +16), staging granule
  int r0, r1;    // compute rows (batch indices)
  int c0, c1;    // compute cols (block-local)
  int kp;
  bool owner;    // kp==0 lanes own the reduced outputs
};

__device__ __forceinline__ TMap make_tmap(int tid) {
  TMap m;
  const int lane = tid & 63, wave = tid >> 6;
  const int kp = lane >> 4, rp2 = (lane >> 2) & 3, cp2 = lane & 3;
  const int wr0 = (wave >> 1) * 8, wc0 = (wave & 1) * 8;
  m.kp = kp;
  m.owner = (kp == 0);
  m.r0 = wr0 + rp2;
  m.r1 = m.r0 + 4;
  m.c0 = wc0 + 2 * cp2;
  m.c1 = m.c0 + 1;
  m.sg0 = m.r0 * 34 + kp;
  m.sg1 = m.r1 * 34 + kp;
  m.w0 = kp * 16 + ((m.c0 + kp) & 15);
  m.w1 = kp * 16 + ((m.c1 + kp) & 15);
  m.rs0 = tid >> 5;
  m.gs = tid & 31;
  m.ws0 = m.rs0 * 34 + m.gs;
  m.ws1 = (m.rs0 + 16) * 34 + m.gs;
  return m;
}

// 4-way K reduction across kp lane groups (lane bits 4,5).
__device__ __forceinline__ void reduce4(float (&a)[4]) {
  #pragma unroll
  for (int i = 0; i < 4; ++i) {
    float v = a[i];
    v += __shfl_xor(v, 16);
    v += __shfl_xor(v, 32);
    a[i] = v;
  }
}

// stage-load one 128-float chunk (this thread's 2 granules of 2 rows)
__device__ __forceinline__ void ld_st(St& s, const u64* p0, const u64* p1,
                                      int ch) {
  s.r0.q[0] = lda64(p0 + ch * 64);
  s.r0.q[1] = lda64(p0 + ch * 64 + 1);
  s.r1.q[0] = lda64(p1 + ch * 64);
  s.r1.q[1] = lda64(p1 + ch * 64 + 1);
}

template <int NMAT>
__device__ __forceinline__ void chunk_compute(const float4* __restrict__ sbuf,
                                              const float4* __restrict__ wA,
                                              const float4* __restrict__ wB,
                                              const TMap& m,
                                              float (&acc)[NMAT][4]) {
  #pragma unroll
  for (int j = 0; j < 8; ++j) {
    float4 s0 = sbuf[m.sg0 + 4 * j];
    float4 s1 = sbuf[m.sg1 + 4 * j];
    float4 a0 = wA[m.w0 + 64 * j];
    float4 a1 = wA[m.w1 + 64 * j];
    FMA4(acc[0][0], s0, a0)
    FMA4(acc[0][1], s0, a1)
    FMA4(acc[0][2], s1, a0)
    FMA4(acc[0][3], s1, a1)
    if constexpr (NMAT == 2) {
      float4 b0 = wB[m.w0 + 64 * j];
      float4 b1 = wB[m.w1 + 64 * j];
      FMA4(acc[1][0], s0, b0)
      FMA4(acc[1][1], s0, b1)
      FMA4(acc[1][2], s1, b0)
      FMA4(acc[1][3], s1, b1)
    }
  }
}

// S[32][1024] (LLC) dot weights-in-LDS -> acc (partial over this thread's K).
// NMAT=2 computes two 16-col column-sets sharing the staged state.
template <int NMAT>
__device__ __forceinline__ void matdot(const float* __restrict__ S,
                                       const float4* __restrict__ wA,
                                       const float4* __restrict__ wB,
                                       float4* __restrict__ sbuf,
                                       const TMap& m, float (&acc)[NMAT][4]) {
  const u64* p0 = (const u64*)S + m.rs0 * 512 + m.gs * 2;
  const u64* p1 = p0 + 16 * 512;
  St st0, st1;
  ld_st(st0, p0, p1, 0);
  ld_st(st1, p0, p1, 1);
  #pragma unroll 1
  for (int cp = 0; cp < 4; ++cp) {
    const int ch = 2 * cp;
    barrier_lds();  // previous chunk's readers done
    sbuf[m.ws0] = st0.r0.f;
    sbuf[m.ws1] = st0.r1.f;
    if (cp < 3) ld_st(st0, p0, p1, ch + 2);  // 2-deep prefetch (vm stays out)
    barrier_lds();  // chunk visible
    chunk_compute<NMAT>(sbuf, wA + ch * 512, wB + ch * 512, m, acc);
    barrier_lds();
    sbuf[m.ws0] = st1.r0.f;
    sbuf[m.ws1] = st1.r1.f;
    if (cp < 3) ld_st(st1, p0, p1, ch + 3);
    barrier_lds();
    chunk_compute<NMAT>(sbuf, wA + (ch + 1) * 512, wB + (ch + 1) * 512, m, acc);
  }
}

// x-projection partial (this thread's 16-wide K slice), K=64 input dim.
__device__ __forceinline__ void xproj(const float* __restrict__ xr0,
                                      const float* __restrict__ xr1,
                                      const float* __restrict__ w0,
                                      const float* __restrict__ w1,
                                      float (&a)[4]) {
  #pragma unroll
  for (int k = 0; k < 16; k += 4) {
    float4 sx0 = *(const float4*)(xr0 + k);
    float4 sx1 = *(const float4*)(xr1 + k);
    float4 wa = *(const float4*)(w0 + k);
    float4 wb = *(const float4*)(w1 + k);
    FMA4(a[0], sx0, wa)
    FMA4(a[1], sx0, wb)
    FMA4(a[2], sx1, wa)
    FMA4(a[3], sx1, wb)
  }
}

// weight preload: 16 cols of W (rows n0..n0+15) into 4096 LDS granules.
// slot = k4*16 + ((c + (k4&3)) & 15): kp-dependent column swizzle so the 4
// kp groups' reads hit different bank quads. Matches matdot's w0/w1 offsets.
__device__ __forceinline__ void load_w16(float4* dst,
                                         const float* __restrict__ W, int n0,
                                         int tid) {
  #pragma unroll
  for (int i = 0; i < 8; ++i) {
    int idx = tid + i * NTHREADS;  // 0..4095
    int c = idx >> 8;              // 0..15
    int k4 = idx & 255;            // 0..255
    int slot = (k4 << 4) | ((c + (k4 & 3)) & 15);
    dst[slot] = *(const float4*)(W + (size_t)(n0 + c) * 1024 + k4 * 4);
  }
}

__global__ __launch_bounds__(NTHREADS) void drmn_persistent(
    const float* __restrict__ x, const float* __restrict__ Wm1,
    const float* __restrict__ Vm1, const float* __restrict__ Wm2,
    const float* __restrict__ Vm2, const float* __restrict__ Win1,
    const float* __restrict__ Wh1, const float* __restrict__ Wmh1,
    const float* __restrict__ b1, const float* __restrict__ Win2,
    const float* __restrict__ Wh2, const float* __restrict__ Wmh2,
    const float* __restrict__ b2, float* __restrict__ out, float* ws,
    int* flags) {
  extern __shared__ float4 smem[];
  float4* w4f = smem;            // [8192] weight granules (128 KiB)
  float4* sbuf = smem + 8192;    // [32*34] state chunk

  const int blk = blockIdx.x;
  const int tid = threadIdx.x;

  float* m1s = ws;                  // [2][B][M]
  float* m2s = m1s + 2 * BB * MM;   // [2][B][M]
  float* h1s = m2s + 2 * BB * MM;   // [2][B][H]
  float* h2s = h1s + 2 * BB * MM;   // [2][B][H]
  float* g2a = h2s + 2 * BB * MM;   // [B][H]

  int* m1c = flags;  // each [T]
  int* m2c = m1c + TT;
  int* h1c = m2c + TT;
  int* h2c = h1c + TT;
  int* g2c = h2c + TT;

  const TMap m = make_tmap(tid);
  const int rr[4] = {m.r0, m.r0, m.r1, m.r1};
  const int cc[4] = {m.c0, m.c1, m.c0, m.c1};

  if (blk < 32) {
    // ================= M1 =================
    const int n0 = blk * 32;
    load_w16(w4f, Vm1, n0, tid);
    load_w16(w4f + 4096, Vm1, n0 + 16, tid);
    __syncthreads();
    const float* wxa0 = Wm1 + (size_t)(n0 + m.c0) * II + m.kp * 16;
    const float* wxa1 = Wm1 + (size_t)(n0 + m.c1) * II + m.kp * 16;
    const float* wxb0 = Wm1 + (size_t)(n0 + 16 + m.c0) * II + m.kp * 16;
    const float* wxb1 = Wm1 + (size_t)(n0 + 16 + m.c1) * II + m.kp * 16;
    for (int t = 0; t < TT; ++t) {
      const float* rd = m1s + (t & 1) * BB * MM;
      float* wr = m1s + ((t & 1) ^ 1) * BB * MM;
      if (t >= 1) wait_flag(&m1c[t - 1], 32);  // full prev state readable
      float acc[2][4] = {};
      const float* xr0 = x + ((size_t)m.r0 * TT + t) * II + m.kp * 16;
      const float* xr1 = x + ((size_t)m.r1 * TT + t) * II + m.kp * 16;
      xproj(xr0, xr1, wxa0, wxa1, acc[0]);
      xproj(xr0, xr1, wxb0, wxb1, acc[1]);
      matdot<2>(rd, w4f, w4f + 4096, sbuf, m, acc);
      reduce4(acc[0]);
      reduce4(acc[1]);
      if (t >= 2) wait_flag(&m2c[t - 2], 64);  // write-buffer free (sunk)
      if (m.owner) {
        #pragma unroll
        for (int i = 0; i < 4; ++i) {
          sta(wr + (size_t)rr[i] * MM + n0 + cc[i], acc[0][i]);
          sta(wr + (size_t)rr[i] * MM + n0 + 16 + cc[i], acc[1][i]);
        }
      }
      post_flag(&m1c[t]);
    }
  } else if (blk < 96) {
    // ================= M2 =================
    const int n0 = (blk - 32) * 16;
    load_w16(w4f, Vm2, n0, tid);
    load_w16(w4f + 4096, Wm2, n0, tid);
    __syncthreads();
    for (int t = 0; t < TT; ++t) {
      const float* rd = m2s + (t & 1) * BB * MM;
      float* wr = m2s + ((t & 1) ^ 1) * BB * MM;
      const float* rdm1 = m1s + ((t & 1) ^ 1) * BB * MM;  // m1_new (this tick)
      if (t >= 1) wait_flag(&m2c[t - 1], 64);
      float acc[1][4] = {};
      matdot<1>(rd, w4f, w4f, sbuf, m, acc);              // Vm2 part
      wait_flag(&m1c[t], 32);
      matdot<1>(rdm1, w4f + 4096, w4f + 4096, sbuf, m, acc);  // Wm2 part
      reduce4(acc[0]);
      if (t >= 2) {  // write-buffer free (sunk)
        wait_flag(&h1c[t - 2], 64);
        wait_flag(&h2c[t - 2], 64);
      }
      if (m.owner) {
        #pragma unroll
        for (int i = 0; i < 4; ++i)
          sta(wr + (size_t)rr[i] * MM + n0 + cc[i], acc[0][i]);
      }
      post_flag(&m2c[t]);
    }
  } else if (blk < 160) {
    // ================= H1 =================
    const int n0 = (blk - 96) * 16;
    load_w16(w4f, Wh1, n0, tid);
    load_w16(w4f + 4096, Wmh1, n0, tid);
    __syncthreads();
    const float* wi0 = Win1 + (size_t)(n0 + m.c0) * II + m.kp * 16;
    const float* wi1 = Win1 + (size_t)(n0 + m.c1) * II + m.kp * 16;
    const float bs[2] = {b1[n0 + m.c0], b1[n0 + m.c1]};
    float h1p[4] = {};  // owner lanes' private h1 state (4 outputs)
    for (int t = 0; t < TT; ++t) {
      const float* rdh = h1s + (t & 1) * BB * HHH;
      float* wrh = h1s + ((t & 1) ^ 1) * BB * HHH;
      const float* rdm2 = m2s + ((t & 1) ^ 1) * BB * MM;  // m2_new
      if (t >= 1) wait_flag(&h1c[t - 1], 64);
      float acc[1][4] = {};
      const float* xr0 = x + ((size_t)m.r0 * TT + t) * II + m.kp * 16;
      const float* xr1 = x + ((size_t)m.r1 * TT + t) * II + m.kp * 16;
      xproj(xr0, xr1, wi0, wi1, acc[0]);
      matdot<1>(rdh, w4f, w4f, sbuf, m, acc);             // Wh1 part
      wait_flag(&m2c[t], 64);
      matdot<1>(rdm2, w4f + 4096, w4f + 4096, sbuf, m, acc);  // Wmh1 part
      reduce4(acc[0]);
      if (t >= 2) wait_flag(&h2c[t - 2], 64);  // write-buffer free (sunk)
      if (m.owner) {
        #pragma unroll
        for (int i = 0; i < 4; ++i) {
          float hn = (1.0f - ALEAK) * h1p[i] +
                     ALEAK * tanhf(acc[0][i] + bs[i & 1]);
          h1p[i] = hn;
          sta(wrh + (size_t)rr[i] * HHH + n0 + cc[i], hn);
        }
      }
      post_flag(&h1c[t]);
    }
  } else if (blk < 224) {
    // ================= H2 main =================
    const int n0 = (blk - 160) * 16;
    load_w16(w4f, Wmh2, n0, tid);
    load_w16(w4f + 4096, Win2, n0, tid);
    __syncthreads();
    float h2p[4] = {};
    for (int t = 0; t < TT; ++t) {
      float* wrh = h2s + ((t & 1) ^ 1) * BB * HHH;
      const float* rdm2 = m2s + ((t & 1) ^ 1) * BB * MM;   // m2_new
      const float* rdh1 = h1s + ((t & 1) ^ 1) * BB * HHH;  // h1_new
      wait_flag(&m2c[t], 64);
      float acc[1][4] = {};
      matdot<1>(rdm2, w4f, w4f, sbuf, m, acc);            // Wmh2 part
      wait_flag(&h1c[t], 64);
      matdot<1>(rdh1, w4f + 4096, w4f + 4096, sbuf, m, acc);  // Win2 part
      reduce4(acc[0]);
      wait_flag(&g2c[t], 32);
      if (m.owner) {
        #pragma unroll
        for (int i = 0; i < 4; ++i) {
          float g = lda(g2a + (size_t)rr[i] * HHH + n0 + cc[i]);
          float hn = (1.0f - ALEAK) * h2p[i] + ALEAK * tanhf(acc[0][i] + g);
          h2p[i] = hn;
          sta(wrh + (size_t)rr[i] * HHH + n0 + cc[i], hn);
          out[((size_t)rr[i] * TT + t) * HHH + n0 + cc[i]] = hn;
        }
      }
      post_flag(&h2c[t]);
    }
  } else {
    // ================= G2 (Wh2 partial + b2) =================
    const int n0 = (blk - 224) * 32;
    load_w16(w4f, Wh2, n0, tid);
    load_w16(w4f + 4096, Wh2, n0 + 16, tid);
    __syncthreads();
    const float bA[2] = {b2[n0 + m.c0], b2[n0 + m.c1]};
    const float bBv[2] = {b2[n0 + 16 + m.c0], b2[n0 + 16 + m.c1]};
    for (int t = 0; t < TT; ++t) {
      const float* rdh = h2s + (t & 1) * BB * HHH;  // h2_old
      if (t >= 1) wait_flag(&h2c[t - 1], 64);  // also: g2a consumer done
      float acc[2][4] = {};
      matdot<2>(rdh, w4f, w4f + 4096, sbuf, m, acc);
      reduce4(acc[0]);
      reduce4(acc[1]);
      if (m.owner) {
        #pragma unroll
        for (int i = 0; i < 4; ++i) {
          sta(g2a + (size_t)rr[i] * HHH + n0 + cc[i], acc[0][i] + bA[i & 1]);
          sta(g2a + (size_t)rr[i] * HHH + n0 + 16 + cc[i],
              acc[1][i] + bBv[i & 1]);
        }
      }
      post_flag(&g2c[t]);
    }
  }
}

extern "C" void kernel_launch(void* const* d_in, const int* in_sizes, int n_in,
                              void* d_out, int out_size, void* d_ws,
                              size_t ws_size, hipStream_t stream) {
  const float* xin  = (const float*)d_in[0];
  const float* Wm1  = (const float*)d_in[1];
  const float* Vm1  = (const float*)d_in[2];
  const float* Wm2  = (const float*)d_in[3];
  const float* Vm2  = (const float*)d_in[4];
  const float* Win1 = (const float*)d_in[5];
  const float* Wh1  = (const float*)d_in[6];
  const float* Wmh1 = (const float*)d_in[7];
  const float* b1   = (const float*)d_in[8];
  const float* Win2 = (const float*)d_in[9];
  const float* Wh2  = (const float*)d_in[10];
  const float* Wmh2 = (const float*)d_in[11];
  const float* b2   = (const float*)d_in[12];
  float* out = (float*)d_out;

  float* ws = (float*)d_ws;
  const size_t data_floats = (size_t)8 * BB * MM + (size_t)BB * HHH;
  int* flags = (int*)(ws + data_floats);
  const size_t clear_bytes =
      data_floats * sizeof(float) + (size_t)5 * TT * sizeof(int);
  hipMemsetAsync(d_ws, 0, clear_bytes, stream);  // zero states + flags

  const int lds_bytes = (8192 + 32 * 34) * 16;  // 148480 B
  static bool cfg = false;
  if (!cfg) {
    (void)hipFuncSetAttribute((const void*)drmn_persistent,
                              hipFuncAttributeMaxDynamicSharedMemorySize,
                              lds_bytes);
    cfg = true;
  }

  drmn_persistent<<<256, NTHREADS, lds_bytes, stream>>>(
      xin, Wm1, Vm1, Wm2, Vm2, Win1, Wh1, Wmh1, b1, Win2, Wh2, Wmh2, b2, out,
      ws, flags);
}